// Round 1
// baseline (865.045 us; speedup 1.0000x reference)
//
#include <hip/hip_runtime.h>

#define DIN 256
#define DH  128
#define DE  64

// ---------------------------------------------------------------- CSR build

__global__ void init_counts_kernel(int* __restrict__ counts, int n) {
    int i = blockIdx.x * blockDim.x + threadIdx.x;
    if (i < n) counts[i] = 0;
}

__global__ void count_edges_kernel(const int* __restrict__ dst,
                                   int* __restrict__ counts, int E) {
    int e = blockIdx.x * blockDim.x + threadIdx.x;
    if (e < E) atomicAdd(&counts[dst[e]], 1);
}

__global__ void dinv_kernel(const int* __restrict__ counts,
                            float* __restrict__ dinv, int n) {
    int i = blockIdx.x * blockDim.x + threadIdx.x;
    if (i < n) dinv[i] = rsqrtf((float)counts[i] + 1.0f);
}

// block of 256 threads scans 1024 elements (4/thread)
__global__ void scan1_kernel(const int* __restrict__ counts,
                             int* __restrict__ rowptr,
                             int* __restrict__ blocksums, int n) {
    __shared__ int sd[256];
    int t = threadIdx.x;
    int base = blockIdx.x * 1024 + t * 4;
    int v[4];
#pragma unroll
    for (int i = 0; i < 4; i++) v[i] = (base + i < n) ? counts[base + i] : 0;
    int tsum = v[0] + v[1] + v[2] + v[3];
    sd[t] = tsum;
    __syncthreads();
    for (int off = 1; off < 256; off <<= 1) {
        int x = (t >= off) ? sd[t - off] : 0;
        __syncthreads();
        sd[t] += x;
        __syncthreads();
    }
    int p = sd[t] - tsum;  // exclusive prefix of this thread
#pragma unroll
    for (int i = 0; i < 4; i++) {
        if (base + i < n) rowptr[base + i] = p;
        p += v[i];
    }
    if (t == 255) blocksums[blockIdx.x] = sd[255];
}

__global__ void scan2_kernel(int* __restrict__ blocksums, int nb) {
    if (threadIdx.x == 0 && blockIdx.x == 0) {
        int run = 0;
        for (int i = 0; i < nb; i++) {
            int x = blocksums[i];
            blocksums[i] = run;
            run += x;
        }
    }
}

__global__ void scan3_kernel(int* __restrict__ rowptr, int* __restrict__ cursor,
                             const int* __restrict__ blocksums, int n, int E) {
    int i = blockIdx.x * blockDim.x + threadIdx.x;
    if (i < n) {
        int r = rowptr[i] + blocksums[i >> 10];
        rowptr[i] = r;
        cursor[i] = r;
    }
    if (i == 0) rowptr[n] = E;
}

__global__ void fill_csr_kernel(const int* __restrict__ src,
                                const int* __restrict__ dst,
                                const float* __restrict__ dinv,
                                int* __restrict__ cursor,
                                int* __restrict__ csr_src,
                                float* __restrict__ csr_coef, int E) {
    int e = blockIdx.x * blockDim.x + threadIdx.x;
    if (e >= E) return;
    int s = src[e], d = dst[e];
    int pos = atomicAdd(&cursor[d], 1);
    csr_src[pos] = s;
    csr_coef[pos] = dinv[s] * dinv[d];
}

// ---------------------------------------------------------------- fp32 GEMM
// C[M,N] = A[M,K] * W[K,N] (+ bias) (+ relu).  64x64 block tile, BK=16,
// 256 threads, 4x4 microtile/thread. K % 16 == 0, N % 64 == 0 assumed.

__global__ __launch_bounds__(256) void gemm_kernel(
    const float* __restrict__ A, const float* __restrict__ W,
    const float* __restrict__ bias, float* __restrict__ C,
    int M, int K, int N, int relu) {
    __shared__ float As[16][64];   // [k][m]
    __shared__ float Bs[16][64];   // [k][n]
    int tid = threadIdx.x;
    int tx = tid & 15, ty = tid >> 4;
    int row0 = blockIdx.x * 64, col0 = blockIdx.y * 64;

    float acc[4][4] = {};

    int ar = tid >> 2, ac = (tid & 3) * 4;    // A loader: tile row, k-offset
    int br = tid >> 4, bc = (tid & 15) * 4;   // B loader: k-row, col-offset
    int garow = row0 + ar;

    for (int k0 = 0; k0 < K; k0 += 16) {
        float4 av;
        if (garow < M)
            av = *(const float4*)&A[(size_t)garow * K + k0 + ac];
        else
            av = make_float4(0.f, 0.f, 0.f, 0.f);
        float4 bv = *(const float4*)&W[(size_t)(k0 + br) * N + col0 + bc];

        As[ac + 0][ar] = av.x;
        As[ac + 1][ar] = av.y;
        As[ac + 2][ar] = av.z;
        As[ac + 3][ar] = av.w;
        *(float4*)&Bs[br][bc] = bv;
        __syncthreads();

#pragma unroll
        for (int kk = 0; kk < 16; kk++) {
            float4 a = *(const float4*)&As[kk][ty * 4];
            float4 b = *(const float4*)&Bs[kk][tx * 4];
            acc[0][0] = fmaf(a.x, b.x, acc[0][0]);
            acc[0][1] = fmaf(a.x, b.y, acc[0][1]);
            acc[0][2] = fmaf(a.x, b.z, acc[0][2]);
            acc[0][3] = fmaf(a.x, b.w, acc[0][3]);
            acc[1][0] = fmaf(a.y, b.x, acc[1][0]);
            acc[1][1] = fmaf(a.y, b.y, acc[1][1]);
            acc[1][2] = fmaf(a.y, b.z, acc[1][2]);
            acc[1][3] = fmaf(a.y, b.w, acc[1][3]);
            acc[2][0] = fmaf(a.z, b.x, acc[2][0]);
            acc[2][1] = fmaf(a.z, b.y, acc[2][1]);
            acc[2][2] = fmaf(a.z, b.z, acc[2][2]);
            acc[2][3] = fmaf(a.z, b.w, acc[2][3]);
            acc[3][0] = fmaf(a.w, b.x, acc[3][0]);
            acc[3][1] = fmaf(a.w, b.y, acc[3][1]);
            acc[3][2] = fmaf(a.w, b.z, acc[3][2]);
            acc[3][3] = fmaf(a.w, b.w, acc[3][3]);
        }
        __syncthreads();
    }

    float4 bv = make_float4(0.f, 0.f, 0.f, 0.f);
    if (bias) bv = *(const float4*)&bias[col0 + tx * 4];
#pragma unroll
    for (int i = 0; i < 4; i++) {
        int r = row0 + ty * 4 + i;
        if (r >= M) continue;
        float4 c;
        c.x = acc[i][0] + bv.x;
        c.y = acc[i][1] + bv.y;
        c.z = acc[i][2] + bv.z;
        c.w = acc[i][3] + bv.w;
        if (relu) {
            c.x = fmaxf(c.x, 0.f);
            c.y = fmaxf(c.y, 0.f);
            c.z = fmaxf(c.z, 0.f);
            c.w = fmaxf(c.w, 0.f);
        }
        *(float4*)&C[(size_t)r * N + col0 + tx * 4] = c;
    }
}

// ------------------------------------------------------------- aggregation
// out[v] = sum_{e: dst==v} h[src_e]*coef_e + h[v]*dinv[v]^2 + bias (, relu)

template <int D, bool RELU>
__global__ __launch_bounds__(256) void agg_kernel(
    const float* __restrict__ h, const float* __restrict__ dinv,
    const int* __restrict__ rowptr, const int* __restrict__ csr_src,
    const float* __restrict__ csr_coef, const float* __restrict__ bias,
    float* __restrict__ out, int n) {
    constexpr int NPB = 256 / D;
    int v = blockIdx.x * NPB + threadIdx.x / D;
    int d = threadIdx.x & (D - 1);
    if (v >= n) return;
    float di = dinv[v];
    float acc = h[(size_t)v * D + d] * (di * di) + bias[d];
    int e0 = rowptr[v], e1 = rowptr[v + 1];
    for (int e = e0; e < e1; e++) {
        int s = csr_src[e];
        float c = csr_coef[e];
        acc = fmaf(h[(size_t)s * D + d], c, acc);
    }
    if (RELU) acc = fmaxf(acc, 0.f);
    out[(size_t)v * D + d] = acc;
}

// ---------------------------------------------------------------- launcher

extern "C" void kernel_launch(void* const* d_in, const int* in_sizes, int n_in,
                              void* d_out, int out_size, void* d_ws,
                              size_t ws_size, hipStream_t stream) {
    const float* x   = (const float*)d_in[0];
    const int*   ei  = (const int*)d_in[1];
    const float* W1  = (const float*)d_in[2];
    const float* b1  = (const float*)d_in[3];
    const float* W2  = (const float*)d_in[4];
    const float* b2  = (const float*)d_in[5];
    const float* W3  = (const float*)d_in[6];
    const float* b3  = (const float*)d_in[7];
    const float* Wd1 = (const float*)d_in[8];
    const float* bd1 = (const float*)d_in[9];
    const float* Wd2 = (const float*)d_in[10];
    const float* bd2 = (const float*)d_in[11];

    const int N = in_sizes[0] / DIN;
    const int E = in_sizes[1] / 2;
    const int* src = ei;
    const int* dst = ei + E;

    char* w = (char*)d_ws;
    auto alloc = [&](size_t bytes) -> char* {
        char* p = w;
        w += (bytes + 255) & ~(size_t)255;
        return p;
    };
    int*   counts    = (int*)alloc((size_t)N * 4);
    float* dinv      = (float*)alloc((size_t)N * 4);
    int*   rowptr    = (int*)alloc((size_t)(N + 1) * 4);
    int*   cursor    = (int*)alloc((size_t)N * 4);
    int*   blocksums = (int*)alloc(4096);
    int*   csr_src   = (int*)alloc((size_t)E * 4);
    float* csr_coef  = (float*)alloc((size_t)E * 4);
    float* Abuf      = (float*)alloc((size_t)N * DH * 4);

    float* zout = (float*)d_out;              // [N, 64]
    float* xhat = zout + (size_t)N * DE;      // [N, 256]
    float* S1   = xhat;                       // scratch (N*128 <= N*256)

    dim3 blk(256);
    int gN = (N + 255) / 256, gE = (E + 255) / 256;

    init_counts_kernel<<<gN, blk, 0, stream>>>(counts, N);
    count_edges_kernel<<<gE, blk, 0, stream>>>(dst, counts, E);
    dinv_kernel<<<gN, blk, 0, stream>>>(counts, dinv, N);
    int nb = (N + 1023) / 1024;
    scan1_kernel<<<nb, blk, 0, stream>>>(counts, rowptr, blocksums, N);
    scan2_kernel<<<1, 64, 0, stream>>>(blocksums, nb);
    scan3_kernel<<<gN, blk, 0, stream>>>(rowptr, cursor, blocksums, N, E);
    fill_csr_kernel<<<gE, blk, 0, stream>>>(src, dst, dinv, cursor, csr_src,
                                            csr_coef, E);

    int mt = (N + 63) / 64;

    // h1 = relu(agg(x @ W1) + b1)
    gemm_kernel<<<dim3(mt, DH / 64), blk, 0, stream>>>(x, W1, nullptr, S1, N,
                                                       DIN, DH, 0);
    agg_kernel<DH, true><<<dim3((N + 1) / 2), blk, 0, stream>>>(
        S1, dinv, rowptr, csr_src, csr_coef, b1, Abuf, N);
    // h2 = relu(agg(h1 @ W2) + b2)
    gemm_kernel<<<dim3(mt, DH / 64), blk, 0, stream>>>(Abuf, W2, nullptr, S1, N,
                                                       DH, DH, 0);
    agg_kernel<DH, true><<<dim3((N + 1) / 2), blk, 0, stream>>>(
        S1, dinv, rowptr, csr_src, csr_coef, b2, Abuf, N);
    // z = agg(h2 @ W3) + b3
    gemm_kernel<<<dim3(mt, DE / 64), blk, 0, stream>>>(Abuf, W3, nullptr, S1, N,
                                                       DH, DE, 0);
    agg_kernel<DE, false><<<dim3((N + 3) / 4), blk, 0, stream>>>(
        S1, dinv, rowptr, csr_src, csr_coef, b3, zout, N);
    // x_hat = relu(z @ Wd1 + bd1) @ Wd2 + bd2
    gemm_kernel<<<dim3(mt, DH / 64), blk, 0, stream>>>(zout, Wd1, bd1, Abuf, N,
                                                       DE, DH, 1);
    gemm_kernel<<<dim3(mt, DIN / 64), blk, 0, stream>>>(Abuf, Wd2, bd2, xhat, N,
                                                        DH, DIN, 0);
}

// Round 2
// 691.838 us; speedup vs baseline: 1.2504x; 1.2504x over previous
//
#include <hip/hip_runtime.h>

#define DIN 256
#define DH  128
#define DE  64

// ---------------------------------------------------------------- CSR build

__global__ void init_counts_kernel(int* __restrict__ counts, int n) {
    int i = blockIdx.x * blockDim.x + threadIdx.x;
    if (i < n) counts[i] = 0;
}

__global__ void count_edges_kernel(const int* __restrict__ dst,
                                   int* __restrict__ counts, int E) {
    int e = blockIdx.x * blockDim.x + threadIdx.x;
    if (e < E) atomicAdd(&counts[dst[e]], 1);
}

__global__ void dinv_kernel(const int* __restrict__ counts,
                            float* __restrict__ dinv, int n) {
    int i = blockIdx.x * blockDim.x + threadIdx.x;
    if (i < n) dinv[i] = rsqrtf((float)counts[i] + 1.0f);
}

// block of 256 threads scans 1024 elements (4/thread)
__global__ void scan1_kernel(const int* __restrict__ counts,
                             int* __restrict__ rowptr,
                             int* __restrict__ blocksums, int n) {
    __shared__ int sd[256];
    int t = threadIdx.x;
    int base = blockIdx.x * 1024 + t * 4;
    int v[4];
#pragma unroll
    for (int i = 0; i < 4; i++) v[i] = (base + i < n) ? counts[base + i] : 0;
    int tsum = v[0] + v[1] + v[2] + v[3];
    sd[t] = tsum;
    __syncthreads();
    for (int off = 1; off < 256; off <<= 1) {
        int x = (t >= off) ? sd[t - off] : 0;
        __syncthreads();
        sd[t] += x;
        __syncthreads();
    }
    int p = sd[t] - tsum;  // exclusive prefix of this thread
#pragma unroll
    for (int i = 0; i < 4; i++) {
        if (base + i < n) rowptr[base + i] = p;
        p += v[i];
    }
    if (t == 255) blocksums[blockIdx.x] = sd[255];
}

__global__ void scan2_kernel(int* __restrict__ blocksums, int nb) {
    if (threadIdx.x == 0 && blockIdx.x == 0) {
        int run = 0;
        for (int i = 0; i < nb; i++) {
            int x = blocksums[i];
            blocksums[i] = run;
            run += x;
        }
    }
}

__global__ void scan3_kernel(int* __restrict__ rowptr, int* __restrict__ cursor,
                             const int* __restrict__ blocksums, int n, int E) {
    int i = blockIdx.x * blockDim.x + threadIdx.x;
    if (i < n) {
        int r = rowptr[i] + blocksums[i >> 10];
        rowptr[i] = r;
        cursor[i] = r;
    }
    if (i == 0) rowptr[n] = E;
}

__global__ void fill_csr_kernel(const int* __restrict__ src,
                                const int* __restrict__ dst,
                                const float* __restrict__ dinv,
                                int* __restrict__ cursor,
                                int* __restrict__ csr_src,
                                float* __restrict__ csr_coef, int E) {
    int e = blockIdx.x * blockDim.x + threadIdx.x;
    if (e >= E) return;
    int s = src[e], d = dst[e];
    int pos = atomicAdd(&cursor[d], 1);
    csr_src[pos] = s;
    csr_coef[pos] = dinv[s] * dinv[d];
}

// ---------------------------------------------------------------- fp32 GEMM
// C[M,N] = A[M,K] * W[K,N] (+ bias) (+ relu).
// 128x64 block tile, BK=32, 256 threads, 8x4 microtile/thread.
// K % 32 == 0, N % 64 == 0 assumed.

__global__ __launch_bounds__(256) void gemm_kernel(
    const float* __restrict__ A, const float* __restrict__ W,
    const float* __restrict__ bias, float* __restrict__ C,
    int M, int K, int N, int relu) {
    // pads: 132/68 keep float4 rows 16B-aligned; write conflicts <= 4-way
    __shared__ float As[32][132];   // [k][m]
    __shared__ float Bs[32][68];    // [k][n]
    int tid = threadIdx.x;
    int tx = tid & 15;              // -> cols tx*4
    int ty = tid >> 4;              // -> rows ty*8
    int row0 = blockIdx.x * 128, col0 = blockIdx.y * 64;

    float acc[8][4] = {};

    int a_kq = (tid & 7) * 4;       // k offset within 32
    int a_r  = tid >> 3;            // row 0..31 (+32*i)
    int b_c  = (tid & 15) * 4;
    int b_kr = tid >> 4;            // k row 0..15 (+16*i)

    for (int k0 = 0; k0 < K; k0 += 32) {
        // stage A (transpose to [k][m]): 4 x float4 per thread
#pragma unroll
        for (int i = 0; i < 4; i++) {
            int r = a_r + i * 32;
            int gr = row0 + r;
            float4 v = make_float4(0.f, 0.f, 0.f, 0.f);
            if (gr < M) v = *(const float4*)&A[(size_t)gr * K + k0 + a_kq];
            As[a_kq + 0][r] = v.x;
            As[a_kq + 1][r] = v.y;
            As[a_kq + 2][r] = v.z;
            As[a_kq + 3][r] = v.w;
        }
        // stage B: 2 x float4 per thread
#pragma unroll
        for (int i = 0; i < 2; i++) {
            int kr = b_kr + i * 16;
            *(float4*)&Bs[kr][b_c] =
                *(const float4*)&W[(size_t)(k0 + kr) * N + col0 + b_c];
        }
        __syncthreads();

#pragma unroll 8
        for (int kk = 0; kk < 32; kk++) {
            float4 a0 = *(const float4*)&As[kk][ty * 8];
            float4 a1 = *(const float4*)&As[kk][ty * 8 + 4];
            float4 b  = *(const float4*)&Bs[kk][tx * 4];
            float am[8] = {a0.x, a0.y, a0.z, a0.w, a1.x, a1.y, a1.z, a1.w};
#pragma unroll
            for (int i = 0; i < 8; i++) {
                acc[i][0] = fmaf(am[i], b.x, acc[i][0]);
                acc[i][1] = fmaf(am[i], b.y, acc[i][1]);
                acc[i][2] = fmaf(am[i], b.z, acc[i][2]);
                acc[i][3] = fmaf(am[i], b.w, acc[i][3]);
            }
        }
        __syncthreads();
    }

    float4 bv = make_float4(0.f, 0.f, 0.f, 0.f);
    if (bias) bv = *(const float4*)&bias[col0 + tx * 4];
#pragma unroll
    for (int i = 0; i < 8; i++) {
        int r = row0 + ty * 8 + i;
        if (r >= M) continue;
        float4 c;
        c.x = acc[i][0] + bv.x;
        c.y = acc[i][1] + bv.y;
        c.z = acc[i][2] + bv.z;
        c.w = acc[i][3] + bv.w;
        if (relu) {
            c.x = fmaxf(c.x, 0.f);
            c.y = fmaxf(c.y, 0.f);
            c.z = fmaxf(c.z, 0.f);
            c.w = fmaxf(c.w, 0.f);
        }
        *(float4*)&C[(size_t)r * N + col0 + tx * 4] = c;
    }
}

// ------------------------------------------------------------- aggregation
// out[v] = sum_{e: dst==v} h[src_e]*coef_e + h[v]*dinv[v]^2 + bias (, relu)
// float4/lane, D/4 lanes per node, 2-edge unroll with dual accumulators.

template <int D, bool RELU>
__global__ __launch_bounds__(256) void agg_kernel(
    const float* __restrict__ h, const float* __restrict__ dinv,
    const int* __restrict__ rowptr, const int* __restrict__ csr_src,
    const float* __restrict__ csr_coef, const float* __restrict__ bias,
    float* __restrict__ out, int n) {
    constexpr int TPN = D / 4;          // threads per node
    constexpr int NPB = 256 / TPN;      // nodes per block
    int v = blockIdx.x * NPB + threadIdx.x / TPN;
    int d4 = (threadIdx.x % TPN) * 4;
    if (v >= n) return;

    float di = dinv[v];
    float s2 = di * di;
    float4 hv = *(const float4*)&h[(size_t)v * D + d4];
    float4 bv = *(const float4*)&bias[d4];
    float4 acc0, acc1;
    acc0.x = fmaf(hv.x, s2, bv.x);
    acc0.y = fmaf(hv.y, s2, bv.y);
    acc0.z = fmaf(hv.z, s2, bv.z);
    acc0.w = fmaf(hv.w, s2, bv.w);
    acc1 = make_float4(0.f, 0.f, 0.f, 0.f);

    int e0 = rowptr[v], e1 = rowptr[v + 1];
    int e = e0;
    for (; e + 2 <= e1; e += 2) {
        int s0 = csr_src[e];
        int s1 = csr_src[e + 1];
        float c0 = csr_coef[e];
        float c1 = csr_coef[e + 1];
        float4 g0 = *(const float4*)&h[(size_t)s0 * D + d4];
        float4 g1 = *(const float4*)&h[(size_t)s1 * D + d4];
        acc0.x = fmaf(g0.x, c0, acc0.x);
        acc0.y = fmaf(g0.y, c0, acc0.y);
        acc0.z = fmaf(g0.z, c0, acc0.z);
        acc0.w = fmaf(g0.w, c0, acc0.w);
        acc1.x = fmaf(g1.x, c1, acc1.x);
        acc1.y = fmaf(g1.y, c1, acc1.y);
        acc1.z = fmaf(g1.z, c1, acc1.z);
        acc1.w = fmaf(g1.w, c1, acc1.w);
    }
    if (e < e1) {
        int s0 = csr_src[e];
        float c0 = csr_coef[e];
        float4 g0 = *(const float4*)&h[(size_t)s0 * D + d4];
        acc0.x = fmaf(g0.x, c0, acc0.x);
        acc0.y = fmaf(g0.y, c0, acc0.y);
        acc0.z = fmaf(g0.z, c0, acc0.z);
        acc0.w = fmaf(g0.w, c0, acc0.w);
    }
    float4 r;
    r.x = acc0.x + acc1.x;
    r.y = acc0.y + acc1.y;
    r.z = acc0.z + acc1.z;
    r.w = acc0.w + acc1.w;
    if (RELU) {
        r.x = fmaxf(r.x, 0.f);
        r.y = fmaxf(r.y, 0.f);
        r.z = fmaxf(r.z, 0.f);
        r.w = fmaxf(r.w, 0.f);
    }
    *(float4*)&out[(size_t)v * D + d4] = r;
}

// ---------------------------------------------------------------- launcher

extern "C" void kernel_launch(void* const* d_in, const int* in_sizes, int n_in,
                              void* d_out, int out_size, void* d_ws,
                              size_t ws_size, hipStream_t stream) {
    const float* x   = (const float*)d_in[0];
    const int*   ei  = (const int*)d_in[1];
    const float* W1  = (const float*)d_in[2];
    const float* b1  = (const float*)d_in[3];
    const float* W2  = (const float*)d_in[4];
    const float* b2  = (const float*)d_in[5];
    const float* W3  = (const float*)d_in[6];
    const float* b3  = (const float*)d_in[7];
    const float* Wd1 = (const float*)d_in[8];
    const float* bd1 = (const float*)d_in[9];
    const float* Wd2 = (const float*)d_in[10];
    const float* bd2 = (const float*)d_in[11];

    const int N = in_sizes[0] / DIN;
    const int E = in_sizes[1] / 2;
    const int* src = ei;
    const int* dst = ei + E;

    char* w = (char*)d_ws;
    auto alloc = [&](size_t bytes) -> char* {
        char* p = w;
        w += (bytes + 255) & ~(size_t)255;
        return p;
    };
    int*   counts    = (int*)alloc((size_t)N * 4);
    float* dinv      = (float*)alloc((size_t)N * 4);
    int*   rowptr    = (int*)alloc((size_t)(N + 1) * 4);
    int*   cursor    = (int*)alloc((size_t)N * 4);
    int*   blocksums = (int*)alloc(4096);
    int*   csr_src   = (int*)alloc((size_t)E * 4);
    float* csr_coef  = (float*)alloc((size_t)E * 4);
    float* Abuf      = (float*)alloc((size_t)N * DH * 4);

    float* zout = (float*)d_out;              // [N, 64]
    float* xhat = zout + (size_t)N * DE;      // [N, 256]
    float* S1   = xhat;                       // scratch (N*128 <= N*256)

    dim3 blk(256);
    int gN = (N + 255) / 256, gE = (E + 255) / 256;

    init_counts_kernel<<<gN, blk, 0, stream>>>(counts, N);
    count_edges_kernel<<<gE, blk, 0, stream>>>(dst, counts, E);
    dinv_kernel<<<gN, blk, 0, stream>>>(counts, dinv, N);
    int nb = (N + 1023) / 1024;
    scan1_kernel<<<nb, blk, 0, stream>>>(counts, rowptr, blocksums, N);
    scan2_kernel<<<1, 64, 0, stream>>>(blocksums, nb);
    scan3_kernel<<<gN, blk, 0, stream>>>(rowptr, cursor, blocksums, N, E);
    fill_csr_kernel<<<gE, blk, 0, stream>>>(src, dst, dinv, cursor, csr_src,
                                            csr_coef, E);

    int mt = (N + 127) / 128;

    // h1 = relu(agg(x @ W1) + b1)
    gemm_kernel<<<dim3(mt, DH / 64), blk, 0, stream>>>(x, W1, nullptr, S1, N,
                                                       DIN, DH, 0);
    agg_kernel<DH, true><<<dim3((N + 7) / 8), blk, 0, stream>>>(
        S1, dinv, rowptr, csr_src, csr_coef, b1, Abuf, N);
    // h2 = relu(agg(h1 @ W2) + b2)
    gemm_kernel<<<dim3(mt, DH / 64), blk, 0, stream>>>(Abuf, W2, nullptr, S1, N,
                                                       DH, DH, 0);
    agg_kernel<DH, true><<<dim3((N + 7) / 8), blk, 0, stream>>>(
        S1, dinv, rowptr, csr_src, csr_coef, b2, Abuf, N);
    // z = agg(h2 @ W3) + b3
    gemm_kernel<<<dim3(mt, DE / 64), blk, 0, stream>>>(Abuf, W3, nullptr, S1, N,
                                                       DH, DE, 0);
    agg_kernel<DE, false><<<dim3((N + 15) / 16), blk, 0, stream>>>(
        S1, dinv, rowptr, csr_src, csr_coef, b3, zout, N);
    // x_hat = relu(z @ Wd1 + bd1) @ Wd2 + bd2
    gemm_kernel<<<dim3(mt, DH / 64), blk, 0, stream>>>(zout, Wd1, bd1, Abuf, N,
                                                       DE, DH, 1);
    gemm_kernel<<<dim3(mt, DIN / 64), blk, 0, stream>>>(Abuf, Wd2, bd2, xhat, N,
                                                        DH, DIN, 0);
}